// Round 5
// baseline (44.481 us; speedup 1.0000x reference)
//
#include <hip/hip_runtime.h>
#include <math.h>

// ParagraphVector fused forward, 16-lane-group-per-dot, phase-decoupled:
//   review_emb = review_emb_table[review_ids]                     [B,128]
//   pos[b,w]   = dot(review_word_emb[b,w,:], review_emb[b,:])
//   neg[b,w,j] = dot(word_emb_table[neg_idxs[b,w*NN+j]], review_emb[b,:])
//   loss[b]    = sum_w mask*(sp(-pos) + sum_j sp(neg)) / max(sum mask,1)
//
// One wave per review; quarter-wave (16 lanes) owns one dot per pass.
// Round-5 change: the per-pass {load -> fma -> butterfly -> softplus} serial
// chain is split into 4 flat phases over all NP passes so the compiler can
// keep many of the 30 independent row-loads in flight (round-4 VGPR=36 ->
// only ~2-3 loads in flight = latency-bound). All shfls outside divergence
// (ds_bpermute returns 0 for EXEC=0 source lanes - round-3 bug).

__device__ __forceinline__ float stable_softplus(float x) {
    // softplus(x) = max(x,0) + log1p(exp(-|x|))  -- overflow-safe
    return fmaxf(x, 0.0f) + log1pf(__expf(-fabsf(x)));
}

template<int W, int NN>
__global__ void __launch_bounds__(256, 4)
pv_spec_kernel(const int* __restrict__ review_ids,      // [B]
               const float* __restrict__ rw_emb,        // [B, W, 128]
               const float* __restrict__ mask,          // [B, W]
               const int* __restrict__ neg_idxs,        // [B, W*NN]
               const float* __restrict__ word_tab,      // [VOCAB, 128]
               const float* __restrict__ rev_tab,       // [RC, 128]
               float* __restrict__ out_rev,             // [B, 128]
               float* __restrict__ out_loss,            // [B]
               int B)
{
    constexpr int E  = 128;
    constexpr int WN = W * NN;            // 50
    constexpr int ND = W + WN;            // 60 dots
    constexpr int NP = (ND + 3) / 4;      // 15 passes, 4 dots each

    const int wave = threadIdx.x >> 6;
    const int lane = threadIdx.x & 63;
    const int b = blockIdx.x * (blockDim.x >> 6) + wave;
    if (b >= B) return;

    const int sub = lane >> 4;     // quarter-wave (dot slot) 0..3
    const int sl  = lane & 15;     // lane within group

    // ---- review embedding: 2 x float4 per lane (replicated across groups) ----
    const int rid = review_ids[b];
    const float4 rv1 = *reinterpret_cast<const float4*>(
        rev_tab + (size_t)rid * E + sl * 4);
    const float4 rv2 = *reinterpret_cast<const float4*>(
        rev_tab + (size_t)rid * E + 64 + sl * 4);

    // output 0: gathered review embedding (lanes 0..31 cover 128 dims)
    if (lane < 16) {
        *reinterpret_cast<float4*>(out_rev + (size_t)b * E + lane * 4) = rv1;
    } else if (lane < 32) {
        *reinterpret_cast<float4*>(out_rev + (size_t)b * E + lane * 4) = rv2;
    }

    // ---- coalesced prefetch of idxs and per-dot masks ----
    const int idx_l = (lane < WN) ? neg_idxs[(size_t)b * WN + lane] : 0;
    float md_l = 0.0f;
    if (lane < ND) {
        const int w = (lane < W) ? lane : (lane - W) / NN;
        md_l = mask[(size_t)b * W + w];
    }

    // ---- phase 1: all row pointers + masks (shfls hoisted, no divergence) ----
    const float* rows[NP];
    float msk[NP];
    #pragma unroll
    for (int p = 0; p < NP; ++p) {
        const int d = p * 4 + sub;
        const bool is_pos = (d < W);
        const bool valid  = (d < ND);
        const int  ni     = __shfl(idx_l, valid ? (is_pos ? 0 : (d - W)) : 0);
        const float m_raw = __shfl(md_l, valid ? d : 0);
        msk[p] = valid ? m_raw : 0.0f;
        rows[p] = is_pos ? rw_emb + ((size_t)b * W + d) * E
                         : word_tab + (size_t)ni * E;
    }

    // ---- phase 2: all loads + 15 independent MAC chains ----
    float acc[NP];
    #pragma unroll
    for (int p = 0; p < NP; ++p) {
        const float4 x1 = *reinterpret_cast<const float4*>(rows[p] + sl * 4);
        const float4 x2 = *reinterpret_cast<const float4*>(rows[p] + 64 + sl * 4);
        float v;
        v = x1.x * rv1.x;
        v = fmaf(x1.y, rv1.y, v);
        v = fmaf(x1.z, rv1.z, v);
        v = fmaf(x1.w, rv1.w, v);
        v = fmaf(x2.x, rv2.x, v);
        v = fmaf(x2.y, rv2.y, v);
        v = fmaf(x2.z, rv2.z, v);
        v = fmaf(x2.w, rv2.w, v);
        acc[p] = v;
    }

    // ---- phase 3: 15 independent 4-step group butterflies ----
    #pragma unroll
    for (int p = 0; p < NP; ++p) {
        float v = acc[p];
        v += __shfl_xor(v, 1);
        v += __shfl_xor(v, 2);
        v += __shfl_xor(v, 4);
        v += __shfl_xor(v, 8);
        acc[p] = v;
    }

    // ---- phase 4: parallel softplus + accumulate ----
    float loss_acc = 0.0f;
    #pragma unroll
    for (int p = 0; p < NP; ++p) {
        const int d = p * 4 + sub;
        const float sgn = (d < W) ? -1.0f : 1.0f;
        loss_acc += msk[p] * stable_softplus(sgn * acc[p]);
    }
    loss_acc = (sl == 0) ? loss_acc : 0.0f;

    // ---- final wave reduction: loss sum + word count ----
    float cntv = (lane < W) ? md_l : 0.0f;   // md_l = mask[b*W+lane] for lane<W
    #pragma unroll
    for (int s = 32; s >= 1; s >>= 1) {
        loss_acc += __shfl_xor(loss_acc, s);
        cntv     += __shfl_xor(cntv, s);
    }

    if (lane == 0) {
        out_loss[b] = loss_acc / fmaxf(cntv, 1.0f);
    }
}

// Generic fallback for shapes other than (W=10, NN=5).
__global__ void __launch_bounds__(256, 4)
pv_generic_kernel(const int* __restrict__ review_ids,
                  const float* __restrict__ rw_emb,
                  const float* __restrict__ mask,
                  const int* __restrict__ neg_idxs,
                  const float* __restrict__ word_tab,
                  const float* __restrict__ rev_tab,
                  float* __restrict__ out_rev,
                  float* __restrict__ out_loss,
                  int B, int W, int NN)
{
    const int wave = threadIdx.x >> 6;
    const int lane = threadIdx.x & 63;
    const int b = blockIdx.x * (blockDim.x >> 6) + wave;
    if (b >= B) return;

    const int E   = 128;
    const int sub = lane >> 4;
    const int sl  = lane & 15;
    const int WN  = W * NN;
    const int nd  = W + WN;

    const int rid = review_ids[b];
    const float4 rv1 = *reinterpret_cast<const float4*>(
        rev_tab + (size_t)rid * E + sl * 4);
    const float4 rv2 = *reinterpret_cast<const float4*>(
        rev_tab + (size_t)rid * E + 64 + sl * 4);
    if (lane < 16) {
        *reinterpret_cast<float4*>(out_rev + (size_t)b * E + lane * 4) = rv1;
    } else if (lane < 32) {
        *reinterpret_cast<float4*>(out_rev + (size_t)b * E + lane * 4) = rv2;
    }

    const int idx_l = (lane < WN) ? neg_idxs[(size_t)b * WN + lane] : 0;
    float md_l = 0.0f;
    if (lane < nd) {
        const int w = (lane < W) ? lane : (lane - W) / NN;
        md_l = mask[(size_t)b * W + w];
    }

    float loss_acc = 0.0f;
    const int npass = (nd + 3) >> 2;
    for (int p = 0; p < npass; ++p) {
        const int d = p * 4 + sub;
        const bool is_pos = (d < W);
        const bool valid  = (d < nd);
        const int  ni     = __shfl(idx_l, valid ? (is_pos ? 0 : (d - W)) : 0);
        const float m_raw = __shfl(md_l, valid ? d : 0);
        const float m     = valid ? m_raw : 0.0f;
        const float* row = is_pos ? rw_emb + ((size_t)b * W + d) * E
                                  : word_tab + (size_t)ni * E;
        const float sgn = is_pos ? -1.0f : 1.0f;
        const float4 x1 = *reinterpret_cast<const float4*>(row + sl * 4);
        const float4 x2 = *reinterpret_cast<const float4*>(row + 64 + sl * 4);
        float v;
        v = x1.x * rv1.x;
        v = fmaf(x1.y, rv1.y, v);
        v = fmaf(x1.z, rv1.z, v);
        v = fmaf(x1.w, rv1.w, v);
        v = fmaf(x2.x, rv2.x, v);
        v = fmaf(x2.y, rv2.y, v);
        v = fmaf(x2.z, rv2.z, v);
        v = fmaf(x2.w, rv2.w, v);
        v += __shfl_xor(v, 1);
        v += __shfl_xor(v, 2);
        v += __shfl_xor(v, 4);
        v += __shfl_xor(v, 8);
        const float term = m * stable_softplus(sgn * v);
        loss_acc += (sl == 0) ? term : 0.0f;
    }

    float cntv = (lane < W) ? md_l : 0.0f;
    #pragma unroll
    for (int s = 32; s >= 1; s >>= 1) {
        loss_acc += __shfl_xor(loss_acc, s);
        cntv     += __shfl_xor(cntv, s);
    }
    if (lane == 0) {
        out_loss[b] = loss_acc / fmaxf(cntv, 1.0f);
    }
}

extern "C" void kernel_launch(void* const* d_in, const int* in_sizes, int n_in,
                              void* d_out, int out_size, void* d_ws, size_t ws_size,
                              hipStream_t stream)
{
    const int*   review_ids = (const int*)  d_in[0];
    const float* rw_emb     = (const float*)d_in[1];
    const float* mask       = (const float*)d_in[2];
    const int*   neg_idxs   = (const int*)  d_in[3];
    const float* word_tab   = (const float*)d_in[4];
    const float* rev_tab    = (const float*)d_in[5];

    const int B  = in_sizes[0];
    const int BW = in_sizes[2];          // B*W
    const int W  = BW / B;
    const int NN = in_sizes[3] / BW;     // n_negs

    float* out_rev  = (float*)d_out;
    float* out_loss = (float*)d_out + (size_t)B * 128;

    const int waves_per_blk = 4;                 // 256 threads
    const int grid = (B + waves_per_blk - 1) / waves_per_blk;

    if (W == 10 && NN == 5) {
        pv_spec_kernel<10, 5><<<grid, 256, 0, stream>>>(
            review_ids, rw_emb, mask, neg_idxs, word_tab, rev_tab,
            out_rev, out_loss, B);
    } else {
        pv_generic_kernel<<<grid, 256, 0, stream>>>(
            review_ids, rw_emb, mask, neg_idxs, word_tab, rev_tab,
            out_rev, out_loss, B, W, NN);
    }
}

// Round 6
// 41.374 us; speedup vs baseline: 1.0751x; 1.0751x over previous
//
#include <hip/hip_runtime.h>
#include <math.h>

// ParagraphVector fused forward, 16-lane-group-per-dot, depth-3 pipelined:
//   review_emb = review_emb_table[review_ids]                     [B,128]
//   pos[b,w]   = dot(review_word_emb[b,w,:], review_emb[b,:])
//   neg[b,w,j] = dot(word_emb_table[neg_idxs[b,w*NN+j]], review_emb[b,:])
//   loss[b]    = sum_w mask*(sp(-pos) + sum_j sp(neg)) / max(sum mask,1)
//
// One wave per review; quarter-wave (16 lanes) owns one dot per pass.
// Round-6 lesson: total MLP = (waves/SIMD) x (loads in flight per wave).
// R4 (VGPR=36): 8 waves/SIMD x ~3 in flight. R5's phase arrays crossed the
// 64-VGPR occupancy cliff: 4 waves/SIMD x ~8 -> wash. This version keeps
// the serial loop (low VGPR, 8 waves/SIMD) and adds an explicit depth-3
// rotating register prefetch (3 x float4-pair = 24 VGPR) so loads for pass
// p+2 are in flight while pass p computes. __launch_bounds__(256,8) pins
// VGPR <= 64. All __shfl's outside divergence (round-3 lesson: ds_bpermute
// returns 0 for EXEC=0 source lanes).

__device__ __forceinline__ float stable_softplus(float x) {
    // softplus(x) = max(x,0) + log1p(exp(-|x|))  -- overflow-safe
    return fmaxf(x, 0.0f) + log1pf(__expf(-fabsf(x)));
}

// Specialized: W=10, NN=5 -> ND=60 dots = exactly 15 passes x 4 groups.
template<int W, int NN>
__global__ void __launch_bounds__(256, 8)
pv_pipe_kernel(const int* __restrict__ review_ids,      // [B]
               const float* __restrict__ rw_emb,        // [B, W, 128]
               const float* __restrict__ mask,          // [B, W]
               const int* __restrict__ neg_idxs,        // [B, W*NN]
               const float* __restrict__ word_tab,      // [VOCAB, 128]
               const float* __restrict__ rev_tab,       // [RC, 128]
               float* __restrict__ out_rev,             // [B, 128]
               float* __restrict__ out_loss,            // [B]
               int B)
{
    constexpr int E  = 128;
    constexpr int WN = W * NN;            // 50
    constexpr int ND = W + WN;            // 60 dots
    constexpr int NP = ND / 4;            // 15 passes (ND % 4 == 0 required)
    static_assert(ND % 4 == 0, "specialized kernel needs ND divisible by 4");

    const int wave = threadIdx.x >> 6;
    const int lane = threadIdx.x & 63;
    const int b = blockIdx.x * (blockDim.x >> 6) + wave;
    if (b >= B) return;

    const int sub = lane >> 4;     // quarter-wave (dot slot) 0..3
    const int sl  = lane & 15;     // lane within group

    // ---- review embedding: 2 x float4 per lane (replicated across groups) ----
    const int rid = review_ids[b];
    const float4 rv1 = *reinterpret_cast<const float4*>(
        rev_tab + (size_t)rid * E + sl * 4);
    const float4 rv2 = *reinterpret_cast<const float4*>(
        rev_tab + (size_t)rid * E + 64 + sl * 4);

    // output 0: gathered review embedding (lanes 0..31 cover 128 dims)
    if (lane < 16) {
        *reinterpret_cast<float4*>(out_rev + (size_t)b * E + lane * 4) = rv1;
    } else if (lane < 32) {
        *reinterpret_cast<float4*>(out_rev + (size_t)b * E + lane * 4) = rv2;
    }

    // ---- coalesced prefetch of idxs and per-dot masks ----
    const int idx_l = (lane < WN) ? neg_idxs[(size_t)b * WN + lane] : 0;
    float md_l = 0.0f;
    if (lane < ND) {
        const int w = (lane < W) ? lane : (lane - W) / NN;
        md_l = mask[(size_t)b * W + w];
    }

    // ---- depth-3 rotating prefetch buffers ----
    float4 bufa[3], bufb[3];

    // issue loads for pass p into buf[p%3]; shfl is divergence-free
    auto issue = [&](int p) {
        const int d = p * 4 + sub;            // 0..ND-1, always valid
        const bool is_pos = (d < W);
        const int ni = __shfl(idx_l, is_pos ? 0 : (d - W));
        const float* row = is_pos ? rw_emb + ((size_t)b * W + d) * E
                                  : word_tab + (size_t)ni * E;
        bufa[p % 3] = *reinterpret_cast<const float4*>(row + sl * 4);
        bufb[p % 3] = *reinterpret_cast<const float4*>(row + 64 + sl * 4);
    };

    issue(0);
    issue(1);

    float loss_acc = 0.0f;
    #pragma unroll
    for (int p = 0; p < NP; ++p) {
        if (p + 2 < NP) issue(p + 2);         // keep 2 passes of loads in flight

        const int d = p * 4 + sub;
        const float m   = __shfl(md_l, d);    // all lanes active, d < 64
        const float sgn = (d < W) ? -1.0f : 1.0f;

        const float4 x1 = bufa[p % 3];
        const float4 x2 = bufb[p % 3];
        float v;
        v = x1.x * rv1.x;
        v = fmaf(x1.y, rv1.y, v);
        v = fmaf(x1.z, rv1.z, v);
        v = fmaf(x1.w, rv1.w, v);
        v = fmaf(x2.x, rv2.x, v);
        v = fmaf(x2.y, rv2.y, v);
        v = fmaf(x2.z, rv2.z, v);
        v = fmaf(x2.w, rv2.w, v);

        // 4-step butterfly within the 16-lane group
        v += __shfl_xor(v, 1);
        v += __shfl_xor(v, 2);
        v += __shfl_xor(v, 4);
        v += __shfl_xor(v, 8);

        const float term = m * stable_softplus(sgn * v);
        loss_acc += (sl == 0) ? term : 0.0f;
    }

    // ---- final wave reduction: loss sum + word count ----
    float cntv = (lane < W) ? md_l : 0.0f;   // md_l = mask[b*W+lane] for lane<W
    #pragma unroll
    for (int s = 32; s >= 1; s >>= 1) {
        loss_acc += __shfl_xor(loss_acc, s);
        cntv     += __shfl_xor(cntv, s);
    }

    if (lane == 0) {
        out_loss[b] = loss_acc / fmaxf(cntv, 1.0f);
    }
}

// Generic fallback for shapes other than (W=10, NN=5).
__global__ void __launch_bounds__(256, 4)
pv_generic_kernel(const int* __restrict__ review_ids,
                  const float* __restrict__ rw_emb,
                  const float* __restrict__ mask,
                  const int* __restrict__ neg_idxs,
                  const float* __restrict__ word_tab,
                  const float* __restrict__ rev_tab,
                  float* __restrict__ out_rev,
                  float* __restrict__ out_loss,
                  int B, int W, int NN)
{
    const int wave = threadIdx.x >> 6;
    const int lane = threadIdx.x & 63;
    const int b = blockIdx.x * (blockDim.x >> 6) + wave;
    if (b >= B) return;

    const int E   = 128;
    const int sub = lane >> 4;
    const int sl  = lane & 15;
    const int WN  = W * NN;
    const int nd  = W + WN;

    const int rid = review_ids[b];
    const float4 rv1 = *reinterpret_cast<const float4*>(
        rev_tab + (size_t)rid * E + sl * 4);
    const float4 rv2 = *reinterpret_cast<const float4*>(
        rev_tab + (size_t)rid * E + 64 + sl * 4);
    if (lane < 16) {
        *reinterpret_cast<float4*>(out_rev + (size_t)b * E + lane * 4) = rv1;
    } else if (lane < 32) {
        *reinterpret_cast<float4*>(out_rev + (size_t)b * E + lane * 4) = rv2;
    }

    const int idx_l = (lane < WN) ? neg_idxs[(size_t)b * WN + lane] : 0;
    float md_l = 0.0f;
    if (lane < nd) {
        const int w = (lane < W) ? lane : (lane - W) / NN;
        md_l = mask[(size_t)b * W + w];
    }

    float loss_acc = 0.0f;
    const int npass = (nd + 3) >> 2;
    for (int p = 0; p < npass; ++p) {
        const int d = p * 4 + sub;
        const bool is_pos = (d < W);
        const bool valid  = (d < nd);
        const int  ni     = __shfl(idx_l, valid ? (is_pos ? 0 : (d - W)) : 0);
        const float m_raw = __shfl(md_l, valid ? d : 0);
        const float m     = valid ? m_raw : 0.0f;
        const float* row = is_pos ? rw_emb + ((size_t)b * W + d) * E
                                  : word_tab + (size_t)ni * E;
        const float sgn = is_pos ? -1.0f : 1.0f;
        const float4 x1 = *reinterpret_cast<const float4*>(row + sl * 4);
        const float4 x2 = *reinterpret_cast<const float4*>(row + 64 + sl * 4);
        float v;
        v = x1.x * rv1.x;
        v = fmaf(x1.y, rv1.y, v);
        v = fmaf(x1.z, rv1.z, v);
        v = fmaf(x1.w, rv1.w, v);
        v = fmaf(x2.x, rv2.x, v);
        v = fmaf(x2.y, rv2.y, v);
        v = fmaf(x2.z, rv2.z, v);
        v = fmaf(x2.w, rv2.w, v);
        v += __shfl_xor(v, 1);
        v += __shfl_xor(v, 2);
        v += __shfl_xor(v, 4);
        v += __shfl_xor(v, 8);
        const float term = m * stable_softplus(sgn * v);
        loss_acc += (sl == 0) ? term : 0.0f;
    }

    float cntv = (lane < W) ? md_l : 0.0f;
    #pragma unroll
    for (int s = 32; s >= 1; s >>= 1) {
        loss_acc += __shfl_xor(loss_acc, s);
        cntv     += __shfl_xor(cntv, s);
    }
    if (lane == 0) {
        out_loss[b] = loss_acc / fmaxf(cntv, 1.0f);
    }
}

extern "C" void kernel_launch(void* const* d_in, const int* in_sizes, int n_in,
                              void* d_out, int out_size, void* d_ws, size_t ws_size,
                              hipStream_t stream)
{
    const int*   review_ids = (const int*)  d_in[0];
    const float* rw_emb     = (const float*)d_in[1];
    const float* mask       = (const float*)d_in[2];
    const int*   neg_idxs   = (const int*)  d_in[3];
    const float* word_tab   = (const float*)d_in[4];
    const float* rev_tab    = (const float*)d_in[5];

    const int B  = in_sizes[0];
    const int BW = in_sizes[2];          // B*W
    const int W  = BW / B;
    const int NN = in_sizes[3] / BW;     // n_negs

    float* out_rev  = (float*)d_out;
    float* out_loss = (float*)d_out + (size_t)B * 128;

    const int waves_per_blk = 4;                 // 256 threads
    const int grid = (B + waves_per_blk - 1) / waves_per_blk;

    if (W == 10 && NN == 5) {
        pv_pipe_kernel<10, 5><<<grid, 256, 0, stream>>>(
            review_ids, rw_emb, mask, neg_idxs, word_tab, rev_tab,
            out_rev, out_loss, B);
    } else {
        pv_generic_kernel<<<grid, 256, 0, stream>>>(
            review_ids, rw_emb, mask, neg_idxs, word_tab, rev_tab,
            out_rev, out_loss, B, W, NN);
    }
}